// Round 4
// baseline (59.807 us; speedup 1.0000x reference)
//
#include <hip/hip_runtime.h>
#include <math.h>

#define B_    16384
#define C_    256
#define N_    128
#define M_    20
#define S_    3
#define EMIT_ 26

// One WAVE (64 lanes) per batch row; 4 independent waves per 256-thread block.
// Zero LDS, zero barriers. FC decomposition: jp=lane&15 -> j-pair (13 valid),
// q=lane>>4 -> quarter of C (64 rows each). W read as float2 (8B-aligned),
// c read redundantly per q-group as float4 from L1 (1KB row, L1-resident).
// Mt / w_prev loads are issued AFTER the FC load stream so vmcnt in-order
// retirement never makes FC wait on HBM-latency loads.
__global__ __launch_bounds__(256, 5) void ntm_wave3_kernel(
    const float* __restrict__ ctrl,    // (B, C)
    const float* __restrict__ w_prev,  // (B, N)
    const float* __restrict__ Mt,      // (B, N, M)
    const float* __restrict__ W,       // (C, EMIT)
    const float* __restrict__ bvec,    // (EMIT)
    float* __restrict__ out)           // (B, N)
{
    const int lane = threadIdx.x & 63;
    const int wid  = threadIdx.x >> 6;
    const int b    = blockIdx.x * 4 + wid;

    const int jp = lane & 15;
    const int jq = (jp > 12) ? 12 : jp;   // j-pair index 0..12 (lanes 13..15 dup)
    const int q  = lane >> 4;             // C quarter

    // ---- FC partials: a0,a1 = sum over this quarter's 64 c-rows ----
    const float* crow = ctrl + (size_t)b * C_ + q * 64;
    const float* Wq   = W + (size_t)(q * 64) * EMIT_ + 2 * jq;
    float a0 = 0.f, a1 = 0.f;
    #pragma unroll
    for (int c4 = 0; c4 < 16; ++c4) {
        const float4 cc = *(const float4*)(crow + c4 * 4);
        #pragma unroll
        for (int u = 0; u < 4; ++u) {
            const float  cv = (&cc.x)[u];
            const float2 wv = *(const float2*)(Wq + (size_t)(c4 * 4 + u) * EMIT_);
            a0 = fmaf(cv, wv.x, a0);
            a1 = fmaf(cv, wv.y, a1);
        }
    }

    // ---- NOW issue the slow HBM loads (Mt rows, w_prev) so their latency
    //      hides under the FC tail; FC never waits on them (issued later). ----
    const float* M0 = Mt + ((size_t)b * N_ + lane) * M_;
    const float* M1 = M0 + (size_t)64 * M_;
    float4 ma[5], mb[5];
    #pragma unroll
    for (int i = 0; i < 5; ++i) ma[i] = *(const float4*)(M0 + 4 * i);
    #pragma unroll
    for (int i = 0; i < 5; ++i) mb[i] = *(const float4*)(M1 + 4 * i);
    const float wp0 = w_prev[(size_t)b * N_ + lane];
    const float wp1 = w_prev[(size_t)b * N_ + lane + 64];

    // ---- reduce partials across the 4 q-groups, bias + tanh ----
    a0 += __shfl_xor(a0, 16);  a0 += __shfl_xor(a0, 32);
    a1 += __shfl_xor(a1, 16);  a1 += __shfl_xor(a1, 32);
    const float2 bb = *(const float2*)(bvec + 2 * jq);
    a0 = tanhf(a0 + bb.x);     // fc[2*jq]
    a1 = tanhf(a1 + bb.y);     // fc[2*jq+1]

    // ---- broadcast all 26 fc values to every lane ----
    float fc[EMIT_];
    #pragma unroll
    for (int j = 0; j < EMIT_; ++j)
        fc[j] = __shfl((j & 1) ? a1 : a0, j >> 1);

    // ---- head parameters (redundant per lane; cheap VALU) ----
    float ksq = 0.f;
    #pragma unroll
    for (int m = 0; m < M_; ++m) ksq = fmaf(fc[m], fc[m], ksq);

    const float beta  = log1pf(__expf(fc[20]));          // softplus (|arg|<1)
    const float g     = 1.f / (1.f + __expf(-fc[21]));   // sigmoid
    const float e0 = __expf(fc[22]);
    const float e1 = __expf(fc[23]);
    const float e2 = __expf(fc[24]);
    const float einv = 1.f / (e0 + e1 + e2);
    const float s0 = e0 * einv, s1 = e1 * einv, s2 = e2 * einv;
    const float gamma = 1.f + log1pf(__expf(fc[25]));

    // ---- cosine similarity logits (Mt data lands in registers by now) ----
    float dot0 = 0.f, msq0 = 0.f, dot1 = 0.f, msq1 = 0.f;
    #pragma unroll
    for (int i = 0; i < 5; ++i) {
        const float4 v = ma[i];
        dot0 = fmaf(fc[4*i+0], v.x, dot0);  msq0 = fmaf(v.x, v.x, msq0);
        dot0 = fmaf(fc[4*i+1], v.y, dot0);  msq0 = fmaf(v.y, v.y, msq0);
        dot0 = fmaf(fc[4*i+2], v.z, dot0);  msq0 = fmaf(v.z, v.z, msq0);
        dot0 = fmaf(fc[4*i+3], v.w, dot0);  msq0 = fmaf(v.w, v.w, msq0);
    }
    #pragma unroll
    for (int i = 0; i < 5; ++i) {
        const float4 v = mb[i];
        dot1 = fmaf(fc[4*i+0], v.x, dot1);  msq1 = fmaf(v.x, v.x, msq1);
        dot1 = fmaf(fc[4*i+1], v.y, dot1);  msq1 = fmaf(v.y, v.y, msq1);
        dot1 = fmaf(fc[4*i+2], v.z, dot1);  msq1 = fmaf(v.z, v.z, msq1);
        dot1 = fmaf(fc[4*i+3], v.w, dot1);  msq1 = fmaf(v.w, v.w, msq1);
    }
    const float l0 = beta * dot0 / sqrtf(ksq * msq0);
    const float l1 = beta * dot1 / sqrtf(ksq * msq1);

    // ---- softmax over the 128 logits (2 per lane, wave butterfly) ----
    float mx = fmaxf(l0, l1);
    #pragma unroll
    for (int o = 32; o; o >>= 1) mx = fmaxf(mx, __shfl_xor(mx, o));
    const float p0 = __expf(l0 - mx);
    const float p1 = __expf(l1 - mx);
    float sm = p0 + p1;
    #pragma unroll
    for (int o = 32; o; o >>= 1) sm += __shfl_xor(sm, o);
    const float inv_sm = 1.f / sm;

    // ---- interpolate with previous weights ----
    const float A  = g * (p0 * inv_sm) + (1.f - g) * wp0;   // wg[lane]
    const float Bv = g * (p1 * inv_sm) + (1.f - g) * wp1;   // wg[lane+64]

    // ---- circular shift: wt[n] = wg[n+1]*s0 + wg[n]*s1 + wg[n-1]*s2 ----
    const float Ap  = __shfl(A,  (lane + 1) & 63);
    const float Bp  = __shfl(Bv, (lane + 1) & 63);
    const float Am  = __shfl(A,  (lane + 63) & 63);
    const float Bm  = __shfl(Bv, (lane + 63) & 63);
    const float A0  = __shfl(A, 0);
    const float A63 = __shfl(A, 63);
    const float B0  = __shfl(Bv, 0);
    const float B63 = __shfl(Bv, 63);

    const float np0 = (lane == 63) ? B0  : Ap;   // wg[(lane+1)   % 128]
    const float nm0 = (lane == 0)  ? B63 : Am;   // wg[(lane-1)   % 128]
    const float np1 = (lane == 63) ? A0  : Bp;   // wg[(lane+65)  % 128]
    const float nm1 = (lane == 0)  ? A63 : Bm;   // wg[(lane+63)  % 128]

    const float wt0 = np0 * s0 + A  * s1 + nm0 * s2;
    const float wt1 = np1 * s0 + Bv * s1 + nm1 * s2;

    // ---- sharpen + normalize ----
    const float wr0 = (wt0 > 0.f) ? __expf(gamma * __logf(wt0)) : 0.f;
    const float wr1 = (wt1 > 0.f) ? __expf(gamma * __logf(wt1)) : 0.f;
    float tot = wr0 + wr1;
    #pragma unroll
    for (int o = 32; o; o >>= 1) tot += __shfl_xor(tot, o);
    const float inv_tot = 1.f / tot;

    float* orow = out + (size_t)b * N_;
    orow[lane]      = wr0 * inv_tot;
    orow[lane + 64] = wr1 * inv_tot;
}

extern "C" void kernel_launch(void* const* d_in, const int* in_sizes, int n_in,
                              void* d_out, int out_size, void* d_ws, size_t ws_size,
                              hipStream_t stream) {
    const float* ctrl   = (const float*)d_in[0];
    const float* w_prev = (const float*)d_in[1];
    const float* Mt     = (const float*)d_in[2];
    const float* W      = (const float*)d_in[3];
    const float* bvec   = (const float*)d_in[4];
    float* out = (float*)d_out;

    ntm_wave3_kernel<<<dim3(B_ / 4), dim3(256), 0, stream>>>(ctrl, w_prev, Mt, W, bvec, out);
}

// Round 5
// 52.620 us; speedup vs baseline: 1.1366x; 1.1366x over previous
//
#include <hip/hip_runtime.h>
#include <math.h>

#define B_    16384
#define C_    256
#define N_    128
#define M_    20
#define S_    3
#define EMIT_ 26

// Wave-uniform broadcast: value from lane `l` into an SGPR (cheap, no LDS).
__device__ __forceinline__ float bcast(float v, int l) {
    return __int_as_float(__builtin_amdgcn_readlane(__float_as_int(v), l));
}

// One WAVE (64 lanes) per batch row; 4 independent waves per 256-thread block.
// Zero LDS, zero barriers.
//  - Mt rows + w_prev are loaded FIRST and pinned with sched_barrier(0) so the
//    compiler cannot sink them (round-4 post-mortem: sinking exposed ~900cy
//    HBM latency serially per wave).
//  - FC: jp=lane&15 -> j-pair (13 valid), q=lane>>4 -> quarter of C.
//    W read as float2, c read as float4 broadcast from L1. 80 VMEM/lane.
//  - fc broadcast via v_readlane -> SGPRs (frees VGPRs for the prefetch).
__global__ __launch_bounds__(256, 4) void ntm_wave4_kernel(
    const float* __restrict__ ctrl,    // (B, C)
    const float* __restrict__ w_prev,  // (B, N)
    const float* __restrict__ Mt,      // (B, N, M)
    const float* __restrict__ W,       // (C, EMIT)
    const float* __restrict__ bvec,    // (EMIT)
    float* __restrict__ out)           // (B, N)
{
    const int lane = threadIdx.x & 63;
    const int wid  = threadIdx.x >> 6;
    const int b    = blockIdx.x * 4 + wid;

    // ---- prefetch the slow HBM data first (Mt rows n=lane, n=lane+64; w_prev) ----
    const float* M0 = Mt + ((size_t)b * N_ + lane) * M_;
    const float* M1 = M0 + (size_t)64 * M_;
    float4 ma[5], mb[5];
    #pragma unroll
    for (int i = 0; i < 5; ++i) ma[i] = *(const float4*)(M0 + 4 * i);
    #pragma unroll
    for (int i = 0; i < 5; ++i) mb[i] = *(const float4*)(M1 + 4 * i);
    const float wp0 = w_prev[(size_t)b * N_ + lane];
    const float wp1 = w_prev[(size_t)b * N_ + lane + 64];
    __builtin_amdgcn_sched_barrier(0);   // pin: do NOT sink these loads

    // ---- FC: fc = tanh(c @ W + b), pair-of-columns per lane ----
    const int jp = lane & 15;
    const int jq = (jp > 12) ? 12 : jp;   // j-pair index 0..12 (lanes 13..15 dup)
    const int q  = lane >> 4;             // C quarter

    const float* crow = ctrl + (size_t)b * C_ + q * 64;
    const float* Wq   = W + (size_t)(q * 64) * EMIT_ + 2 * jq;
    float a0 = 0.f, a1 = 0.f;
    #pragma unroll
    for (int c4 = 0; c4 < 16; ++c4) {
        const float4 cc = *(const float4*)(crow + c4 * 4);
        #pragma unroll
        for (int u = 0; u < 4; ++u) {
            const float  cv = (&cc.x)[u];
            const float2 wv = *(const float2*)(Wq + (size_t)(c4 * 4 + u) * EMIT_);
            a0 = fmaf(cv, wv.x, a0);
            a1 = fmaf(cv, wv.y, a1);
        }
    }

    // ---- reduce partials across the 4 q-groups, bias + tanh ----
    a0 += __shfl_xor(a0, 16);  a0 += __shfl_xor(a0, 32);
    a1 += __shfl_xor(a1, 16);  a1 += __shfl_xor(a1, 32);
    const float2 bb = *(const float2*)(bvec + 2 * jq);
    a0 = tanhf(a0 + bb.x);     // fc[2*jq]
    a1 = tanhf(a1 + bb.y);     // fc[2*jq+1]

    // ---- broadcast all 26 fc values to SGPRs (wave-uniform) ----
    float fc[EMIT_];
    #pragma unroll
    for (int j = 0; j < EMIT_; ++j)
        fc[j] = bcast((j & 1) ? a1 : a0, j >> 1);

    // ---- head parameters (wave-uniform) ----
    float ksq = 0.f;
    #pragma unroll
    for (int m = 0; m < M_; ++m) ksq = fmaf(fc[m], fc[m], ksq);

    const float beta  = log1pf(__expf(fc[20]));          // softplus (|arg|<1)
    const float g     = 1.f / (1.f + __expf(-fc[21]));   // sigmoid
    const float e0 = __expf(fc[22]);
    const float e1 = __expf(fc[23]);
    const float e2 = __expf(fc[24]);
    const float einv = 1.f / (e0 + e1 + e2);
    const float s0 = e0 * einv, s1 = e1 * einv, s2 = e2 * einv;
    const float gamma = 1.f + log1pf(__expf(fc[25]));

    // ---- cosine similarity logits (Mt already in registers) ----
    float dot0 = 0.f, msq0 = 0.f, dot1 = 0.f, msq1 = 0.f;
    #pragma unroll
    for (int i = 0; i < 5; ++i) {
        const float4 v = ma[i];
        dot0 = fmaf(fc[4*i+0], v.x, dot0);  msq0 = fmaf(v.x, v.x, msq0);
        dot0 = fmaf(fc[4*i+1], v.y, dot0);  msq0 = fmaf(v.y, v.y, msq0);
        dot0 = fmaf(fc[4*i+2], v.z, dot0);  msq0 = fmaf(v.z, v.z, msq0);
        dot0 = fmaf(fc[4*i+3], v.w, dot0);  msq0 = fmaf(v.w, v.w, msq0);
    }
    #pragma unroll
    for (int i = 0; i < 5; ++i) {
        const float4 v = mb[i];
        dot1 = fmaf(fc[4*i+0], v.x, dot1);  msq1 = fmaf(v.x, v.x, msq1);
        dot1 = fmaf(fc[4*i+1], v.y, dot1);  msq1 = fmaf(v.y, v.y, msq1);
        dot1 = fmaf(fc[4*i+2], v.z, dot1);  msq1 = fmaf(v.z, v.z, msq1);
        dot1 = fmaf(fc[4*i+3], v.w, dot1);  msq1 = fmaf(v.w, v.w, msq1);
    }
    const float l0 = beta * dot0 / sqrtf(ksq * msq0);
    const float l1 = beta * dot1 / sqrtf(ksq * msq1);

    // ---- softmax over the 128 logits (2 per lane, wave butterfly) ----
    float mx = fmaxf(l0, l1);
    #pragma unroll
    for (int o = 32; o; o >>= 1) mx = fmaxf(mx, __shfl_xor(mx, o));
    const float p0 = __expf(l0 - mx);
    const float p1 = __expf(l1 - mx);
    float sm = p0 + p1;
    #pragma unroll
    for (int o = 32; o; o >>= 1) sm += __shfl_xor(sm, o);
    const float inv_sm = 1.f / sm;

    // ---- interpolate with previous weights ----
    const float A  = g * (p0 * inv_sm) + (1.f - g) * wp0;   // wg[lane]
    const float Bv = g * (p1 * inv_sm) + (1.f - g) * wp1;   // wg[lane+64]

    // ---- circular shift: wt[n] = wg[n+1]*s0 + wg[n]*s1 + wg[n-1]*s2 ----
    const float Ap  = __shfl(A,  (lane + 1) & 63);
    const float Bp  = __shfl(Bv, (lane + 1) & 63);
    const float Am  = __shfl(A,  (lane + 63) & 63);
    const float Bm  = __shfl(Bv, (lane + 63) & 63);
    const float A0  = bcast(A, 0);
    const float A63 = bcast(A, 63);
    const float B0  = bcast(Bv, 0);
    const float B63 = bcast(Bv, 63);

    const float np0 = (lane == 63) ? B0  : Ap;   // wg[(lane+1)   % 128]
    const float nm0 = (lane == 0)  ? B63 : Am;   // wg[(lane-1)   % 128]
    const float np1 = (lane == 63) ? A0  : Bp;   // wg[(lane+65)  % 128]
    const float nm1 = (lane == 0)  ? A63 : Bm;   // wg[(lane+63)  % 128]

    const float wt0 = np0 * s0 + A  * s1 + nm0 * s2;
    const float wt1 = np1 * s0 + Bv * s1 + nm1 * s2;

    // ---- sharpen + normalize ----
    const float wr0 = (wt0 > 0.f) ? __expf(gamma * __logf(wt0)) : 0.f;
    const float wr1 = (wt1 > 0.f) ? __expf(gamma * __logf(wt1)) : 0.f;
    float tot = wr0 + wr1;
    #pragma unroll
    for (int o = 32; o; o >>= 1) tot += __shfl_xor(tot, o);
    const float inv_tot = 1.f / tot;

    float* orow = out + (size_t)b * N_;
    orow[lane]      = wr0 * inv_tot;
    orow[lane + 64] = wr1 * inv_tot;
}

extern "C" void kernel_launch(void* const* d_in, const int* in_sizes, int n_in,
                              void* d_out, int out_size, void* d_ws, size_t ws_size,
                              hipStream_t stream) {
    const float* ctrl   = (const float*)d_in[0];
    const float* w_prev = (const float*)d_in[1];
    const float* Mt     = (const float*)d_in[2];
    const float* W      = (const float*)d_in[3];
    const float* bvec   = (const float*)d_in[4];
    float* out = (float*)d_out;

    ntm_wave4_kernel<<<dim3(B_ / 4), dim3(256), 0, stream>>>(ctrl, w_prev, Mt, W, bvec, out);
}